// Round 15
// baseline (138.235 us; speedup 1.0000x reference)
//
#include <hip/hip_runtime.h>
#include <hip/hip_bf16.h>

#define B_   8
#define U_   8192
#define E_   256
#define N_   32
#define S_   1024
#define MP_  40
#define H_   8
#define NLIST 39
#define NCAP  35          // pool cap: 35 points + grid token = 36 rows
#define NTOKMAX 36
#define GCELLS (B_*S_)     // 8192
#define KDIM  (H_*E_)      // 2048
#define GEMMBLK 512        // GEMM blocks per launch (both GEMMs)

typedef unsigned short ushort_t;
using bf16x8 = __attribute__((ext_vector_type(8))) short;
using f32x4  = __attribute__((ext_vector_type(4))) float;

// ---------------- ws layout (bytes) — verified r5..r14 ----------------
#define WS_COUNTS 0u
#define WS_LISTS  32768u
#define WS_LATB   1310720u
#define WS_WQKT   1835008u
#define WS_WVOT   2883584u
#define WS_QKB    3932160u
#define WS_W      8126464u

__device__ inline unsigned pk2(float a, float b) {
    __hip_bfloat16 x = __float2bfloat16(a), y = __float2bfloat16(b);
    return ((unsigned)(*(ushort_t*)&y) << 16) | (unsigned)(*(ushort_t*)&x);
}
__device__ inline float ubf(ushort_t u) {
    unsigned v = (unsigned)u << 16;
    return *(float*)&v;
}

// ================================================================ K1: prep (r14 branches, re-based; + prologue folded in)
// [0,128): latents->bf16   [128,192): WqkT   [192,224): WvoT
// [224,240): counts zero + xc_on passthrough (must precede build_lists = node 2)
__global__ __launch_bounds__(256)
void prep(const float* __restrict__ latents,
          const float* __restrict__ Wq, const float* __restrict__ Wk,
          const float* __restrict__ Wv, const float* __restrict__ Wo,
          const float* __restrict__ xc_on, float* __restrict__ out,
          int* __restrict__ counts,
          ushort_t* __restrict__ latb, ushort_t* __restrict__ wqkT,
          ushort_t* __restrict__ wvoT) {
    __shared__ float smem[10496];
    int blk = blockIdx.x, tid = threadIdx.x;

    if (blk < 128) {                                    // ---- latents -> bf16 (r14 verbatim logic)
        int i = blk * 256 + tid;                        // 32768 chunks of 8 floats
        const float4* src = (const float4*)latents + 2 * i;
        float4 a = src[0], c = src[1];
        uint4 o;
        o.x = pk2(a.x, a.y); o.y = pk2(a.z, a.w);
        o.z = pk2(c.x, c.y); o.w = pk2(c.z, c.w);
        ((uint4*)latb)[i] = o;
    } else if (blk < 192) {                             // ---- WqkT[(h,e)][f], r14 conflict-free remap
        int b2 = blk - 128, h = b2 >> 3, e0 = (b2 & 7) * 32;
        float* wq_s = smem;                             // [256][33]
        for (int i = tid; i < 8192; i += 256) {
            int f = i >> 5, d = i & 31;
            wq_s[f * 33 + d] = Wq[f * E_ + h * 32 + d];
        }
        __syncthreads();
        int e = e0 + (tid & 31), fg = tid >> 5;         // fg near-wave-uniform
        float wk[32];
        #pragma unroll
        for (int d4 = 0; d4 < 8; ++d4) {
            float4 v = *(const float4*)(Wk + (size_t)e * E_ + h * 32 + d4 * 4);
            wk[d4*4] = v.x; wk[d4*4+1] = v.y; wk[d4*4+2] = v.z; wk[d4*4+3] = v.w;
        }
        const float invs = 0.17677669529663687f;        // 1/sqrt(32)
        ushort_t* dst = wqkT + (size_t)(h * E_ + e) * E_ + fg * 32;
        for (int q8 = 0; q8 < 4; ++q8) {
            float t8[8];
            #pragma unroll
            for (int k = 0; k < 8; ++k) {
                int f = fg * 32 + q8 * 8 + k;
                float acc = 0.f;
                #pragma unroll
                for (int d = 0; d < 32; ++d) acc += wq_s[f * 33 + d] * wk[d];
                t8[k] = acc * invs;
            }
            uint4 o;
            o.x = pk2(t8[0], t8[1]); o.y = pk2(t8[2], t8[3]);
            o.z = pk2(t8[4], t8[5]); o.w = pk2(t8[6], t8[7]);
            *(uint4*)(dst + q8 * 8) = o;
        }
    } else if (blk < 224) {                             // ---- WvoT[e'][(h,e)], r14 remap
        int b3 = blk - 192, h = b3 >> 2, e0p = (b3 & 3) * 64;
        float* wv_s = smem;                             // [256][33]
        float* wo_s = smem + 8448;                      // [32][64]
        for (int i = tid; i < 8192; i += 256) {
            int e = i >> 5, d = i & 31;
            wv_s[e * 33 + d] = Wv[e * E_ + h * 32 + d];
        }
        for (int i = tid; i < 2048; i += 256) {
            int d = i >> 6, el = i & 63;
            wo_s[i] = Wo[(h * 32 + d) * E_ + e0p + el];
        }
        __syncthreads();
        int erow = tid & 63, eg = tid >> 6;             // eg = wave id (uniform)
        float wor[32];
        #pragma unroll
        for (int d = 0; d < 32; ++d) wor[d] = wo_s[d * 64 + erow];
        ushort_t* dst = wvoT + (size_t)(e0p + erow) * KDIM + h * E_ + eg * 64;
        for (int q8 = 0; q8 < 8; ++q8) {
            float t8[8];
            #pragma unroll
            for (int k = 0; k < 8; ++k) {
                int e = eg * 64 + q8 * 8 + k;
                float acc = 0.f;
                #pragma unroll
                for (int d = 0; d < 32; ++d) acc += wv_s[e * 33 + d] * wor[d];
                t8[k] = acc;
            }
            uint4 o;
            o.x = pk2(t8[0], t8[1]); o.y = pk2(t8[2], t8[3]);
            o.z = pk2(t8[4], t8[5]); o.w = pk2(t8[6], t8[7]);
            *(uint4*)(dst + q8 * 8) = o;
        }
    } else {                                            // ---- prologue (r9 verbatim logic)
        int i = (blk - 224) * 256 + tid;                // 0..4095
        ((float4*)out)[i] = ((const float4*)xc_on)[i];  // passthrough
        if (i < 2048) ((int4*)counts)[i] = make_int4(0, 0, 0, 0);
    }
}

// ================================================================ K2/K4: bf16 MFMA GEMM, BK=128
// r9-verified structure with BKT=128 (SPR=16, PT=4, LDB=136 — same mod-32 bank
// class as verified 72). Halves barrier count, 16 MFMA/wave per k-step.
// DO_BUILD: blocks >= GEMMBLK run build_lists (independent work, rides along
// to save one graph node; needs counts zeroed = node 1).
template<int BKT, bool BF16OUT, bool DO_BUILD>
__global__ __launch_bounds__(256)
void gemm_k(const ushort_t* __restrict__ A, const ushort_t* __restrict__ BT,
            void* __restrict__ Cv, int Kdim, int Ndim, int lgNTX,
            const float* __restrict__ xc_off, int* __restrict__ counts,
            int* __restrict__ lists) {
    if (DO_BUILD && (int)blockIdx.x >= GEMMBLK) {       // ---- build_lists (r14 verbatim)
        int t = ((int)blockIdx.x - GEMMBLK) * 256 + threadIdx.x;
        float x = xc_off[2 * t], y = xc_off[2 * t + 1];
        int row = (int)rintf(x * 31.f); row = min(max(row, 0), 31);
        int col = (int)rintf(y * 31.f); col = min(max(col, 0), 31);
        int b = t >> 13;
        int g = b * S_ + row * N_ + col;
        int old = atomicAdd(&counts[g], 1);
        if (old < NLIST) lists[g * NLIST + old] = t & (U_ - 1);
        return;
    }
    constexpr int LDB = BKT + 8;          // 136: 272B row stride ≡ 4 words mod 32 (same class as 72)
    constexpr int SPR = BKT / 8;          // 16 16B-slots per tile row
    constexpr int PT  = 64 * SPR / 256;   // 4 slots/thread/matrix
    __shared__ ushort_t As[64 * LDB];
    __shared__ ushort_t Bs[64 * LDB];
    int tid = threadIdx.x;
    int idx = blockIdx.x;
    idx = (idx & 7) * (GEMMBLK >> 3) + (idx >> 3);      // XCD-chunk swizzle over 512
    int nTX = 1 << lgNTX;
    int m0 = (idx >> lgNTX) * 64, n0 = (idx & (nTX - 1)) * 64;

    int wave = tid >> 6, lane = tid & 63;
    int wr = wave >> 1, wc = wave & 1;
    int l15 = lane & 15, lg = lane >> 4;

    f32x4 acc[2][2];
    #pragma unroll
    for (int m = 0; m < 2; ++m)
        #pragma unroll
        for (int n = 0; n < 2; ++n)
            acc[m][n] = (f32x4){0.f, 0.f, 0.f, 0.f};

    int rr = tid / SPR, uu = tid % SPR;   // base row [0,16), 16B-slot col
    const ushort_t* pa = A  + (size_t)(m0 + rr) * Kdim + uu * 8;
    const ushort_t* pb = BT + (size_t)(n0 + rr) * Kdim + uu * 8;

    uint4 ar[PT], br[PT];
    #pragma unroll
    for (int i = 0; i < PT; ++i) {        // rows rr + i*16
        ar[i] = *(const uint4*)(pa + (size_t)i * 16 * Kdim);
        br[i] = *(const uint4*)(pb + (size_t)i * 16 * Kdim);
    }

    for (int kt = 0; kt < Kdim; kt += BKT) {
        __syncthreads();                  // prev iter's frag reads done
        #pragma unroll
        for (int i = 0; i < PT; ++i) {
            *(uint4*)(As + (rr + i * 16) * LDB + uu * 8) = ar[i];
            *(uint4*)(Bs + (rr + i * 16) * LDB + uu * 8) = br[i];
        }
        __syncthreads();
        if (kt + BKT < Kdim) {            // issue next loads early (hide under MFMA)
            #pragma unroll
            for (int i = 0; i < PT; ++i) {
                ar[i] = *(const uint4*)(pa + (size_t)i * 16 * Kdim + kt + BKT);
                br[i] = *(const uint4*)(pb + (size_t)i * 16 * Kdim + kt + BKT);
            }
        }
        #pragma unroll
        for (int kk = 0; kk < BKT / 32; ++kk) {
            bf16x8 af[2], bfr[2];
            #pragma unroll
            for (int m = 0; m < 2; ++m)
                af[m] = *(const bf16x8*)(As + (wr * 32 + m * 16 + l15) * LDB + (kk * 4 + lg) * 8);
            #pragma unroll
            for (int n = 0; n < 2; ++n)
                bfr[n] = *(const bf16x8*)(Bs + (wc * 32 + n * 16 + l15) * LDB + (kk * 4 + lg) * 8);
            #pragma unroll
            for (int m = 0; m < 2; ++m)
                #pragma unroll
                for (int n = 0; n < 2; ++n)
                    acc[m][n] = __builtin_amdgcn_mfma_f32_16x16x32_bf16(
                        af[m], bfr[n], acc[m][n], 0, 0, 0);
        }
    }
    #pragma unroll
    for (int m = 0; m < 2; ++m)
        #pragma unroll
        for (int n = 0; n < 2; ++n)
            #pragma unroll
            for (int q = 0; q < 4; ++q) {
                int row = m0 + wr * 32 + m * 16 + lg * 4 + q;
                int col = n0 + wc * 32 + n * 16 + l15;
                if (BF16OUT) {
                    __hip_bfloat16 hb = __float2bfloat16(acc[m][n][q]);
                    ((ushort_t*)Cv)[(size_t)row * Ndim + col] = *(ushort_t*)&hb;
                } else {
                    ((float*)Cv)[(size_t)row * Ndim + col] = acc[m][n][q];
                }
            }
}

// ================================================================ K3: pool (r14 verbatim)
__global__ __launch_bounds__(256, 8)
void pool_cells(const float* __restrict__ zc_off, const float* __restrict__ zc_on,
                const float* __restrict__ fake, const ushort_t* __restrict__ qkb,
                const int* __restrict__ counts, const int* __restrict__ lists,
                const int* __restrict__ ig_p, ushort_t* __restrict__ wout) {
    __shared__ __align__(16) ushort_t tok[NTOKMAX * E_];   // 18 KB, swizzled
    __shared__ float sc[H_ * 48];                          // 1.5 KB

    int g = blockIdx.x, s = g & (S_ - 1), b = g >> 10, tid = threadIdx.x;
    int h = tid >> 5, j = tid & 31;

    int cnt = min(counts[g], NCAP);
    int ntok = cnt + 1, ig = ig_p[0];
    const float* lastrow = ig ? fake : zc_on + (size_t)g * E_;

    {
        uint4* t4 = (uint4*)tok;
        for (int i = tid; i < ntok * 32; i += 256) {
            int p = i >> 5, q = i & 31;
            const float* src = (p < cnt)
                ? zc_off + ((size_t)b * U_ + lists[g * NLIST + p]) * E_
                : lastrow;
            float4 x = *(const float4*)(src + q * 8);
            float4 y = *(const float4*)(src + q * 8 + 4);
            uint4 o;
            o.x = pk2(x.x, x.y); o.y = pk2(x.z, x.w);
            o.z = pk2(y.x, y.y); o.w = pk2(y.z, y.w);
            t4[((p << 5) + q) ^ (p & 7)] = o;
        }
    }
    __syncthreads();

    if (tid < 64) {
        int l15 = tid & 15, lg = tid >> 4;
        bf16x8 af[8];
        const ushort_t* qrow = qkb + (size_t)s * KDIM + l15 * E_ + lg * 8;
        #pragma unroll
        for (int kk = 0; kk < 8; ++kk)
            af[kk] = *(const bf16x8*)(qrow + kk * 32);
        const bf16x8* tv = (const bf16x8*)tok;
        int ntiles = (ntok + 15) >> 4;
        for (int t = 0; t < ntiles; ++t) {
            f32x4 acc = (f32x4){0.f, 0.f, 0.f, 0.f};
            int row = t * 16 + l15;
            int rc = row < NTOKMAX ? row : NTOKMAX - 1;
            #pragma unroll
            for (int kk = 0; kk < 8; ++kk) {
                bf16x8 bfr = tv[((rc << 5) + (kk << 2) + lg) ^ (rc & 7)];
                acc = __builtin_amdgcn_mfma_f32_16x16x32_bf16(af[kk], bfr, acc, 0, 0, 0);
            }
            if (lg < 2) {
                #pragma unroll
                for (int q = 0; q < 4; ++q)
                    sc[(lg * 4 + q) * 48 + t * 16 + l15] = acc[q];
            }
        }
    }
    __syncthreads();

    {
        float v0 = (j < ntok) ? sc[h * 48 + j] : -1e30f;
        float v1 = (j + 32 < ntok) ? sc[h * 48 + j + 32] : -1e30f;
        float mx = fmaxf(v0, v1);
        #pragma unroll
        for (int off = 16; off; off >>= 1) mx = fmaxf(mx, __shfl_xor(mx, off, 32));
        float e0 = (j < ntok) ? __expf(v0 - mx) : 0.f;
        float e1 = (j + 32 < ntok) ? __expf(v1 - mx) : 0.f;
        float sm = e0 + e1;
        #pragma unroll
        for (int off = 16; off; off >>= 1) sm += __shfl_xor(sm, off, 32);
        float inv = 1.f / sm;
        if (j < ntok)      sc[h * 48 + j] = e0 * inv;
        if (j + 32 < ntok) sc[h * 48 + j + 32] = e1 * inv;
    }
    // no barrier: same 32-lane group, wave program order (r10-r14 verified)

    float acc[8];
    #pragma unroll
    for (int k = 0; k < 8; ++k) acc[k] = 0.f;
    const bf16x8* tv2 = (const bf16x8*)tok;
    for (int p = 0; p < ntok; ++p) {
        float a = sc[h * 48 + p];
        bf16x8 t8 = tv2[((p << 5) + j) ^ (p & 7)];
        #pragma unroll
        for (int k = 0; k < 8; ++k) acc[k] += a * ubf((ushort_t)t8[k]);
    }
    uint4 o;
    o.x = pk2(acc[0], acc[1]); o.y = pk2(acc[2], acc[3]);
    o.z = pk2(acc[4], acc[5]); o.w = pk2(acc[6], acc[7]);
    ((uint4*)(wout + (size_t)g * KDIM))[tid] = o;
}

// ================================================================ launch — 4 graph nodes
extern "C" void kernel_launch(void* const* d_in, const int* in_sizes, int n_in,
                              void* d_out, int out_size, void* d_ws, size_t ws_size,
                              hipStream_t stream) {
    const float* xc_off  = (const float*)d_in[0];
    const float* xc_on   = (const float*)d_in[1];
    const float* zc_off  = (const float*)d_in[2];
    const float* zc_on   = (const float*)d_in[3];
    const float* latents = (const float*)d_in[4];
    const float* fake    = (const float*)d_in[5];
    const float* Wq      = (const float*)d_in[6];
    const float* Wk      = (const float*)d_in[7];
    const float* Wv      = (const float*)d_in[8];
    const float* Wo      = (const float*)d_in[9];
    const int*   ig      = (const int*)d_in[10];
    float* out = (float*)d_out;

    char* ws = (char*)d_ws;
    int*      counts = (int*)(ws + WS_COUNTS);
    int*      lists  = (int*)(ws + WS_LISTS);
    ushort_t* latb   = (ushort_t*)(ws + WS_LATB);
    ushort_t* wqkT   = (ushort_t*)(ws + WS_WQKT);
    ushort_t* wvoT   = (ushort_t*)(ws + WS_WVOT);
    ushort_t* qkb    = (ushort_t*)(ws + WS_QKB);
    ushort_t* w      = (ushort_t*)(ws + WS_W);

    const int PASS = B_ * N_ * N_ * 2;   // 16384 floats

    // node 1: latb + WqkT + WvoT + counts-zero + passthrough (240 blocks)
    prep<<<240, 256, 0, stream>>>(latents, Wq, Wk, Wv, Wo, xc_on, out,
                                  counts, latb, wqkT, wvoT);

    // node 2: qkb = latb @ WqkT (M=1024 N=2048 K=256, 512 blocks, lgNTX=5)
    //         + build_lists (blocks 512..767)
    gemm_k<128, true, true><<<GEMMBLK + 256, 256, 0, stream>>>(
        latb, wqkT, qkb, 256, KDIM, 5, xc_off, counts, lists);

    // node 3: pool
    pool_cells<<<GCELLS, 256, 0, stream>>>(zc_off, zc_on, fake, qkb,
                                           counts, lists, ig, w);

    // node 4: out = w @ Wvo (M=8192 N=256 K=2048, 512 blocks, lgNTX=2)
    gemm_k<128, false, false><<<GEMMBLK, 256, 0, stream>>>(
        w, wvoT, out + PASS, KDIM, E_, 2, nullptr, nullptr, nullptr);
}

// Round 16
// 79.032 us; speedup vs baseline: 1.7491x; 1.7491x over previous
//
#include <hip/hip_runtime.h>
#include <hip/hip_bf16.h>

#define B_   8
#define U_   8192
#define E_   256
#define N_   32
#define S_   1024
#define MP_  40
#define H_   8
#define NLIST 39
#define NCAP  35          // pool cap: 35 points + grid token = 36 rows
#define NTOKMAX 36
#define GCELLS (B_*S_)     // 8192
#define KDIM  (H_*E_)      // 2048
#define GEMMBLK 512        // GEMM blocks per launch (both GEMMs)

typedef unsigned short ushort_t;
using bf16x8 = __attribute__((ext_vector_type(8))) short;
using f32x4  = __attribute__((ext_vector_type(4))) float;

// ---------------- ws layout (bytes) — verified r5..r15 ----------------
#define WS_COUNTS 0u
#define WS_LISTS  32768u
#define WS_LATB   1310720u
#define WS_WQKT   1835008u
#define WS_WVOT   2883584u
#define WS_QKB    3932160u
#define WS_W      8126464u

__device__ inline unsigned pk2(float a, float b) {
    __hip_bfloat16 x = __float2bfloat16(a), y = __float2bfloat16(b);
    return ((unsigned)(*(ushort_t*)&y) << 16) | (unsigned)(*(ushort_t*)&x);
}
__device__ inline float ubf(ushort_t u) {
    unsigned v = (unsigned)u << 16;
    return *(float*)&v;
}

// ================================================================ K1: prep (r15 verbatim)
// [0,128): latents->bf16   [128,192): WqkT   [192,224): WvoT
// [224,240): counts zero + xc_on passthrough
__global__ __launch_bounds__(256)
void prep(const float* __restrict__ latents,
          const float* __restrict__ Wq, const float* __restrict__ Wk,
          const float* __restrict__ Wv, const float* __restrict__ Wo,
          const float* __restrict__ xc_on, float* __restrict__ out,
          int* __restrict__ counts,
          ushort_t* __restrict__ latb, ushort_t* __restrict__ wqkT,
          ushort_t* __restrict__ wvoT) {
    __shared__ float smem[10496];
    int blk = blockIdx.x, tid = threadIdx.x;

    if (blk < 128) {                                    // ---- latents -> bf16
        int i = blk * 256 + tid;
        const float4* src = (const float4*)latents + 2 * i;
        float4 a = src[0], c = src[1];
        uint4 o;
        o.x = pk2(a.x, a.y); o.y = pk2(a.z, a.w);
        o.z = pk2(c.x, c.y); o.w = pk2(c.z, c.w);
        ((uint4*)latb)[i] = o;
    } else if (blk < 192) {                             // ---- WqkT[(h,e)][f]
        int b2 = blk - 128, h = b2 >> 3, e0 = (b2 & 7) * 32;
        float* wq_s = smem;                             // [256][33]
        for (int i = tid; i < 8192; i += 256) {
            int f = i >> 5, d = i & 31;
            wq_s[f * 33 + d] = Wq[f * E_ + h * 32 + d];
        }
        __syncthreads();
        int e = e0 + (tid & 31), fg = tid >> 5;         // fg near-wave-uniform (conflict-free)
        float wk[32];
        #pragma unroll
        for (int d4 = 0; d4 < 8; ++d4) {
            float4 v = *(const float4*)(Wk + (size_t)e * E_ + h * 32 + d4 * 4);
            wk[d4*4] = v.x; wk[d4*4+1] = v.y; wk[d4*4+2] = v.z; wk[d4*4+3] = v.w;
        }
        const float invs = 0.17677669529663687f;        // 1/sqrt(32)
        ushort_t* dst = wqkT + (size_t)(h * E_ + e) * E_ + fg * 32;
        for (int q8 = 0; q8 < 4; ++q8) {
            float t8[8];
            #pragma unroll
            for (int k = 0; k < 8; ++k) {
                int f = fg * 32 + q8 * 8 + k;
                float acc = 0.f;
                #pragma unroll
                for (int d = 0; d < 32; ++d) acc += wq_s[f * 33 + d] * wk[d];
                t8[k] = acc * invs;
            }
            uint4 o;
            o.x = pk2(t8[0], t8[1]); o.y = pk2(t8[2], t8[3]);
            o.z = pk2(t8[4], t8[5]); o.w = pk2(t8[6], t8[7]);
            *(uint4*)(dst + q8 * 8) = o;
        }
    } else if (blk < 224) {                             // ---- WvoT[e'][(h,e)]
        int b3 = blk - 192, h = b3 >> 2, e0p = (b3 & 3) * 64;
        float* wv_s = smem;                             // [256][33]
        float* wo_s = smem + 8448;                      // [32][64]
        for (int i = tid; i < 8192; i += 256) {
            int e = i >> 5, d = i & 31;
            wv_s[e * 33 + d] = Wv[e * E_ + h * 32 + d];
        }
        for (int i = tid; i < 2048; i += 256) {
            int d = i >> 6, el = i & 63;
            wo_s[i] = Wo[(h * 32 + d) * E_ + e0p + el];
        }
        __syncthreads();
        int erow = tid & 63, eg = tid >> 6;             // eg = wave id (uniform)
        float wor[32];
        #pragma unroll
        for (int d = 0; d < 32; ++d) wor[d] = wo_s[d * 64 + erow];
        ushort_t* dst = wvoT + (size_t)(e0p + erow) * KDIM + h * E_ + eg * 64;
        for (int q8 = 0; q8 < 8; ++q8) {
            float t8[8];
            #pragma unroll
            for (int k = 0; k < 8; ++k) {
                int e = eg * 64 + q8 * 8 + k;
                float acc = 0.f;
                #pragma unroll
                for (int d = 0; d < 32; ++d) acc += wv_s[e * 33 + d] * wor[d];
                t8[k] = acc;
            }
            uint4 o;
            o.x = pk2(t8[0], t8[1]); o.y = pk2(t8[2], t8[3]);
            o.z = pk2(t8[4], t8[5]); o.w = pk2(t8[6], t8[7]);
            *(uint4*)(dst + q8 * 8) = o;
        }
    } else {                                            // ---- prologue
        int i = (blk - 224) * 256 + tid;                // 0..4095
        ((float4*)out)[i] = ((const float4*)xc_on)[i];
        if (i < 2048) ((int4*)counts)[i] = make_int4(0, 0, 0, 0);
    }
}

// ================================================================ K2/K4: bf16 MFMA GEMM — r14 BK=64 body (no spill)
// REVERT from BK=128: that variant's 32 prefetch VGPRs spilled to scratch
// (r15: VGPR=52, WRITE_SIZE 103MB vs 4-8MB output, both GEMMs 74.9us).
// BK=64 holds 16 prefetch regs — verified fast r9-r14. Swizzle over GEMMBLK
// (NOT gridDim.x — grid may include build_lists rider blocks).
template<bool BF16OUT, bool DO_BUILD>
__global__ __launch_bounds__(256)
void gemm_k(const ushort_t* __restrict__ A, const ushort_t* __restrict__ BT,
            void* __restrict__ Cv, int Kdim, int Ndim, int lgNTX,
            const float* __restrict__ xc_off, int* __restrict__ counts,
            int* __restrict__ lists) {
    if (DO_BUILD && (int)blockIdx.x >= GEMMBLK) {       // ---- build_lists rider (r14 verbatim)
        int t = ((int)blockIdx.x - GEMMBLK) * 256 + threadIdx.x;
        float x = xc_off[2 * t], y = xc_off[2 * t + 1];
        int row = (int)rintf(x * 31.f); row = min(max(row, 0), 31);
        int col = (int)rintf(y * 31.f); col = min(max(col, 0), 31);
        int b = t >> 13;
        int g = b * S_ + row * N_ + col;
        int old = atomicAdd(&counts[g], 1);
        if (old < NLIST) lists[g * NLIST + old] = t & (U_ - 1);
        return;
    }
    constexpr int LDB = 72;
    __shared__ ushort_t As[64 * LDB];
    __shared__ ushort_t Bs[64 * LDB];
    int tid = threadIdx.x;
    int idx = blockIdx.x;
    idx = (idx & 7) * (GEMMBLK >> 3) + (idx >> 3);      // bijective over 512
    int nTX = 1 << lgNTX;
    int m0 = (idx >> lgNTX) * 64, n0 = (idx & (nTX - 1)) * 64;

    int wave = tid >> 6, lane = tid & 63;
    int wr = wave >> 1, wc = wave & 1;
    int l15 = lane & 15, lg = lane >> 4;

    f32x4 acc[2][2];
    #pragma unroll
    for (int m = 0; m < 2; ++m)
        #pragma unroll
        for (int n = 0; n < 2; ++n)
            acc[m][n] = (f32x4){0.f, 0.f, 0.f, 0.f};

    int r0 = tid >> 3, u0 = tid & 7;
    int r1 = r0 + 32, u1 = u0;

    const ushort_t* pa0 = A  + (size_t)(m0 + r0) * Kdim + u0 * 8;
    const ushort_t* pa1 = A  + (size_t)(m0 + r1) * Kdim + u1 * 8;
    const ushort_t* pb0 = BT + (size_t)(n0 + r0) * Kdim + u0 * 8;
    const ushort_t* pb1 = BT + (size_t)(n0 + r1) * Kdim + u1 * 8;

    uint4 a0 = *(const uint4*)(pa0);
    uint4 a1 = *(const uint4*)(pa1);
    uint4 b0 = *(const uint4*)(pb0);
    uint4 b1 = *(const uint4*)(pb1);

    for (int kt = 0; kt < Kdim; kt += 64) {
        __syncthreads();                       // prev iter's frag reads done
        *(uint4*)(As + r0 * LDB + u0 * 8) = a0;
        *(uint4*)(As + r1 * LDB + u1 * 8) = a1;
        *(uint4*)(Bs + r0 * LDB + u0 * 8) = b0;
        *(uint4*)(Bs + r1 * LDB + u1 * 8) = b1;
        __syncthreads();
        if (kt + 64 < Kdim) {                  // issue next loads early
            a0 = *(const uint4*)(pa0 + kt + 64);
            a1 = *(const uint4*)(pa1 + kt + 64);
            b0 = *(const uint4*)(pb0 + kt + 64);
            b1 = *(const uint4*)(pb1 + kt + 64);
        }
        #pragma unroll
        for (int kk = 0; kk < 2; ++kk) {
            bf16x8 af[2], bfr[2];
            #pragma unroll
            for (int m = 0; m < 2; ++m)
                af[m] = *(const bf16x8*)(As + (wr * 32 + m * 16 + l15) * LDB + (kk * 4 + lg) * 8);
            #pragma unroll
            for (int n = 0; n < 2; ++n)
                bfr[n] = *(const bf16x8*)(Bs + (wc * 32 + n * 16 + l15) * LDB + (kk * 4 + lg) * 8);
            #pragma unroll
            for (int m = 0; m < 2; ++m)
                #pragma unroll
                for (int n = 0; n < 2; ++n)
                    acc[m][n] = __builtin_amdgcn_mfma_f32_16x16x32_bf16(
                        af[m], bfr[n], acc[m][n], 0, 0, 0);
        }
    }
    #pragma unroll
    for (int m = 0; m < 2; ++m)
        #pragma unroll
        for (int n = 0; n < 2; ++n)
            #pragma unroll
            for (int q = 0; q < 4; ++q) {
                int row = m0 + wr * 32 + m * 16 + lg * 4 + q;
                int col = n0 + wc * 32 + n * 16 + l15;
                if (BF16OUT) {
                    __hip_bfloat16 hb = __float2bfloat16(acc[m][n][q]);
                    ((ushort_t*)Cv)[(size_t)row * Ndim + col] = *(ushort_t*)&hb;
                } else {
                    ((float*)Cv)[(size_t)row * Ndim + col] = acc[m][n][q];
                }
            }
}

// ================================================================ K3: pool (r14/r15 verbatim)
__global__ __launch_bounds__(256, 8)
void pool_cells(const float* __restrict__ zc_off, const float* __restrict__ zc_on,
                const float* __restrict__ fake, const ushort_t* __restrict__ qkb,
                const int* __restrict__ counts, const int* __restrict__ lists,
                const int* __restrict__ ig_p, ushort_t* __restrict__ wout) {
    __shared__ __align__(16) ushort_t tok[NTOKMAX * E_];   // 18 KB, swizzled
    __shared__ float sc[H_ * 48];                          // 1.5 KB

    int g = blockIdx.x, s = g & (S_ - 1), b = g >> 10, tid = threadIdx.x;
    int h = tid >> 5, j = tid & 31;

    int cnt = min(counts[g], NCAP);
    int ntok = cnt + 1, ig = ig_p[0];
    const float* lastrow = ig ? fake : zc_on + (size_t)g * E_;

    {
        uint4* t4 = (uint4*)tok;
        for (int i = tid; i < ntok * 32; i += 256) {
            int p = i >> 5, q = i & 31;
            const float* src = (p < cnt)
                ? zc_off + ((size_t)b * U_ + lists[g * NLIST + p]) * E_
                : lastrow;
            float4 x = *(const float4*)(src + q * 8);
            float4 y = *(const float4*)(src + q * 8 + 4);
            uint4 o;
            o.x = pk2(x.x, x.y); o.y = pk2(x.z, x.w);
            o.z = pk2(y.x, y.y); o.w = pk2(y.z, y.w);
            t4[((p << 5) + q) ^ (p & 7)] = o;
        }
    }
    __syncthreads();

    if (tid < 64) {
        int l15 = tid & 15, lg = tid >> 4;
        bf16x8 af[8];
        const ushort_t* qrow = qkb + (size_t)s * KDIM + l15 * E_ + lg * 8;
        #pragma unroll
        for (int kk = 0; kk < 8; ++kk)
            af[kk] = *(const bf16x8*)(qrow + kk * 32);
        const bf16x8* tv = (const bf16x8*)tok;
        int ntiles = (ntok + 15) >> 4;
        for (int t = 0; t < ntiles; ++t) {
            f32x4 acc = (f32x4){0.f, 0.f, 0.f, 0.f};
            int row = t * 16 + l15;
            int rc = row < NTOKMAX ? row : NTOKMAX - 1;
            #pragma unroll
            for (int kk = 0; kk < 8; ++kk) {
                bf16x8 bfr = tv[((rc << 5) + (kk << 2) + lg) ^ (rc & 7)];
                acc = __builtin_amdgcn_mfma_f32_16x16x32_bf16(af[kk], bfr, acc, 0, 0, 0);
            }
            if (lg < 2) {
                #pragma unroll
                for (int q = 0; q < 4; ++q)
                    sc[(lg * 4 + q) * 48 + t * 16 + l15] = acc[q];
            }
        }
    }
    __syncthreads();

    {
        float v0 = (j < ntok) ? sc[h * 48 + j] : -1e30f;
        float v1 = (j + 32 < ntok) ? sc[h * 48 + j + 32] : -1e30f;
        float mx = fmaxf(v0, v1);
        #pragma unroll
        for (int off = 16; off; off >>= 1) mx = fmaxf(mx, __shfl_xor(mx, off, 32));
        float e0 = (j < ntok) ? __expf(v0 - mx) : 0.f;
        float e1 = (j + 32 < ntok) ? __expf(v1 - mx) : 0.f;
        float sm = e0 + e1;
        #pragma unroll
        for (int off = 16; off; off >>= 1) sm += __shfl_xor(sm, off, 32);
        float inv = 1.f / sm;
        if (j < ntok)      sc[h * 48 + j] = e0 * inv;
        if (j + 32 < ntok) sc[h * 48 + j + 32] = e1 * inv;
    }
    // no barrier: same 32-lane group, wave program order (r10-r15 verified)

    float acc[8];
    #pragma unroll
    for (int k = 0; k < 8; ++k) acc[k] = 0.f;
    const bf16x8* tv2 = (const bf16x8*)tok;
    for (int p = 0; p < ntok; ++p) {
        float a = sc[h * 48 + p];
        bf16x8 t8 = tv2[((p << 5) + j) ^ (p & 7)];
        #pragma unroll
        for (int k = 0; k < 8; ++k) acc[k] += a * ubf((ushort_t)t8[k]);
    }
    uint4 o;
    o.x = pk2(acc[0], acc[1]); o.y = pk2(acc[2], acc[3]);
    o.z = pk2(acc[4], acc[5]); o.w = pk2(acc[6], acc[7]);
    ((uint4*)(wout + (size_t)g * KDIM))[tid] = o;
}

// ================================================================ launch — 4 graph nodes (r15 structure)
extern "C" void kernel_launch(void* const* d_in, const int* in_sizes, int n_in,
                              void* d_out, int out_size, void* d_ws, size_t ws_size,
                              hipStream_t stream) {
    const float* xc_off  = (const float*)d_in[0];
    const float* xc_on   = (const float*)d_in[1];
    const float* zc_off  = (const float*)d_in[2];
    const float* zc_on   = (const float*)d_in[3];
    const float* latents = (const float*)d_in[4];
    const float* fake    = (const float*)d_in[5];
    const float* Wq      = (const float*)d_in[6];
    const float* Wk      = (const float*)d_in[7];
    const float* Wv      = (const float*)d_in[8];
    const float* Wo      = (const float*)d_in[9];
    const int*   ig      = (const int*)d_in[10];
    float* out = (float*)d_out;

    char* ws = (char*)d_ws;
    int*      counts = (int*)(ws + WS_COUNTS);
    int*      lists  = (int*)(ws + WS_LISTS);
    ushort_t* latb   = (ushort_t*)(ws + WS_LATB);
    ushort_t* wqkT   = (ushort_t*)(ws + WS_WQKT);
    ushort_t* wvoT   = (ushort_t*)(ws + WS_WVOT);
    ushort_t* qkb    = (ushort_t*)(ws + WS_QKB);
    ushort_t* w      = (ushort_t*)(ws + WS_W);

    const int PASS = B_ * N_ * N_ * 2;   // 16384 floats

    // node 1: latb + WqkT + WvoT + counts-zero + passthrough (240 blocks)
    prep<<<240, 256, 0, stream>>>(latents, Wq, Wk, Wv, Wo, xc_on, out,
                                  counts, latb, wqkT, wvoT);

    // node 2: qkb = latb @ WqkT (M=1024 N=2048 K=256, 512 blocks, lgNTX=5)
    //         + build_lists (blocks 512..767)
    gemm_k<true, true><<<GEMMBLK + 256, 256, 0, stream>>>(
        latb, wqkT, qkb, 256, KDIM, 5, xc_off, counts, lists);

    // node 3: pool
    pool_cells<<<GCELLS, 256, 0, stream>>>(zc_off, zc_on, fake, qkb,
                                           counts, lists, ig, w);

    // node 4: out = w @ Wvo (M=8192 N=256 K=2048, 512 blocks, lgNTX=2)
    gemm_k<false, false><<<GEMMBLK, 256, 0, stream>>>(
        w, wvoT, out + PASS, KDIM, E_, 2, nullptr, nullptr, nullptr);
}

// Round 17
// 70.498 us; speedup vs baseline: 1.9608x; 1.1211x over previous
//
#include <hip/hip_runtime.h>
#include <hip/hip_bf16.h>

#define B_   8
#define U_   8192
#define E_   256
#define N_   32
#define S_   1024
#define MP_  40
#define H_   8
#define NLIST 39
#define NCAP  35          // pool cap: 35 points + grid token = 36 rows
#define NTOKMAX 36
#define GCELLS (B_*S_)     // 8192
#define KDIM  (H_*E_)      // 2048
#define GEMMBLK 512        // GEMM blocks per launch (both GEMMs)

typedef unsigned short ushort_t;
using bf16x8 = __attribute__((ext_vector_type(8))) short;
using f32x4  = __attribute__((ext_vector_type(4))) float;

// ---------------- ws layout (bytes) — verified r5..r16 ----------------
#define WS_COUNTS 0u
#define WS_LISTS  32768u
#define WS_LATB   1310720u
#define WS_WQKT   1835008u
#define WS_WVOT   2883584u
#define WS_QKB    3932160u
#define WS_W      8126464u

// f32 pair -> packed bf16 via the HW instruction (gfx950 v_cvt_pk_bf16_f32).
// T12 recipe: no builtin exists; src0 -> low half, src1 -> high half.
// Replaces the header's software RNE sequence (this round's single variable).
__device__ inline unsigned pk2(float a, float b) {
    unsigned r;
    asm("v_cvt_pk_bf16_f32 %0, %1, %2" : "=v"(r) : "v"(a), "v"(b));
    return r;
}
__device__ inline float ubf(ushort_t u) {
    unsigned v = (unsigned)u << 16;
    return *(float*)&v;
}

// ================================================================ K1: prep (r16 verbatim)
// [0,128): latents->bf16   [128,192): WqkT   [192,224): WvoT
// [224,240): counts zero + xc_on passthrough
__global__ __launch_bounds__(256)
void prep(const float* __restrict__ latents,
          const float* __restrict__ Wq, const float* __restrict__ Wk,
          const float* __restrict__ Wv, const float* __restrict__ Wo,
          const float* __restrict__ xc_on, float* __restrict__ out,
          int* __restrict__ counts,
          ushort_t* __restrict__ latb, ushort_t* __restrict__ wqkT,
          ushort_t* __restrict__ wvoT) {
    __shared__ float smem[10496];
    int blk = blockIdx.x, tid = threadIdx.x;

    if (blk < 128) {                                    // ---- latents -> bf16
        int i = blk * 256 + tid;
        const float4* src = (const float4*)latents + 2 * i;
        float4 a = src[0], c = src[1];
        uint4 o;
        o.x = pk2(a.x, a.y); o.y = pk2(a.z, a.w);
        o.z = pk2(c.x, c.y); o.w = pk2(c.z, c.w);
        ((uint4*)latb)[i] = o;
    } else if (blk < 192) {                             // ---- WqkT[(h,e)][f]
        int b2 = blk - 128, h = b2 >> 3, e0 = (b2 & 7) * 32;
        float* wq_s = smem;                             // [256][33]
        for (int i = tid; i < 8192; i += 256) {
            int f = i >> 5, d = i & 31;
            wq_s[f * 33 + d] = Wq[f * E_ + h * 32 + d];
        }
        __syncthreads();
        int e = e0 + (tid & 31), fg = tid >> 5;         // fg near-wave-uniform (conflict-free)
        float wk[32];
        #pragma unroll
        for (int d4 = 0; d4 < 8; ++d4) {
            float4 v = *(const float4*)(Wk + (size_t)e * E_ + h * 32 + d4 * 4);
            wk[d4*4] = v.x; wk[d4*4+1] = v.y; wk[d4*4+2] = v.z; wk[d4*4+3] = v.w;
        }
        const float invs = 0.17677669529663687f;        // 1/sqrt(32)
        ushort_t* dst = wqkT + (size_t)(h * E_ + e) * E_ + fg * 32;
        for (int q8 = 0; q8 < 4; ++q8) {
            float t8[8];
            #pragma unroll
            for (int k = 0; k < 8; ++k) {
                int f = fg * 32 + q8 * 8 + k;
                float acc = 0.f;
                #pragma unroll
                for (int d = 0; d < 32; ++d) acc += wq_s[f * 33 + d] * wk[d];
                t8[k] = acc * invs;
            }
            uint4 o;
            o.x = pk2(t8[0], t8[1]); o.y = pk2(t8[2], t8[3]);
            o.z = pk2(t8[4], t8[5]); o.w = pk2(t8[6], t8[7]);
            *(uint4*)(dst + q8 * 8) = o;
        }
    } else if (blk < 224) {                             // ---- WvoT[e'][(h,e)]
        int b3 = blk - 192, h = b3 >> 2, e0p = (b3 & 3) * 64;
        float* wv_s = smem;                             // [256][33]
        float* wo_s = smem + 8448;                      // [32][64]
        for (int i = tid; i < 8192; i += 256) {
            int e = i >> 5, d = i & 31;
            wv_s[e * 33 + d] = Wv[e * E_ + h * 32 + d];
        }
        for (int i = tid; i < 2048; i += 256) {
            int d = i >> 6, el = i & 63;
            wo_s[i] = Wo[(h * 32 + d) * E_ + e0p + el];
        }
        __syncthreads();
        int erow = tid & 63, eg = tid >> 6;             // eg = wave id (uniform)
        float wor[32];
        #pragma unroll
        for (int d = 0; d < 32; ++d) wor[d] = wo_s[d * 64 + erow];
        ushort_t* dst = wvoT + (size_t)(e0p + erow) * KDIM + h * E_ + eg * 64;
        for (int q8 = 0; q8 < 8; ++q8) {
            float t8[8];
            #pragma unroll
            for (int k = 0; k < 8; ++k) {
                int e = eg * 64 + q8 * 8 + k;
                float acc = 0.f;
                #pragma unroll
                for (int d = 0; d < 32; ++d) acc += wv_s[e * 33 + d] * wor[d];
                t8[k] = acc;
            }
            uint4 o;
            o.x = pk2(t8[0], t8[1]); o.y = pk2(t8[2], t8[3]);
            o.z = pk2(t8[4], t8[5]); o.w = pk2(t8[6], t8[7]);
            *(uint4*)(dst + q8 * 8) = o;
        }
    } else {                                            // ---- prologue
        int i = (blk - 224) * 256 + tid;                // 0..4095
        ((float4*)out)[i] = ((const float4*)xc_on)[i];
        if (i < 2048) ((int4*)counts)[i] = make_int4(0, 0, 0, 0);
    }
}

// ================================================================ K2/K4: bf16 MFMA GEMM (r16 verbatim, BK=64)
template<bool BF16OUT, bool DO_BUILD>
__global__ __launch_bounds__(256)
void gemm_k(const ushort_t* __restrict__ A, const ushort_t* __restrict__ BT,
            void* __restrict__ Cv, int Kdim, int Ndim, int lgNTX,
            const float* __restrict__ xc_off, int* __restrict__ counts,
            int* __restrict__ lists) {
    if (DO_BUILD && (int)blockIdx.x >= GEMMBLK) {       // ---- build_lists rider
        int t = ((int)blockIdx.x - GEMMBLK) * 256 + threadIdx.x;
        float x = xc_off[2 * t], y = xc_off[2 * t + 1];
        int row = (int)rintf(x * 31.f); row = min(max(row, 0), 31);
        int col = (int)rintf(y * 31.f); col = min(max(col, 0), 31);
        int b = t >> 13;
        int g = b * S_ + row * N_ + col;
        int old = atomicAdd(&counts[g], 1);
        if (old < NLIST) lists[g * NLIST + old] = t & (U_ - 1);
        return;
    }
    constexpr int LDB = 72;
    __shared__ ushort_t As[64 * LDB];
    __shared__ ushort_t Bs[64 * LDB];
    int tid = threadIdx.x;
    int idx = blockIdx.x;
    idx = (idx & 7) * (GEMMBLK >> 3) + (idx >> 3);      // bijective over 512
    int nTX = 1 << lgNTX;
    int m0 = (idx >> lgNTX) * 64, n0 = (idx & (nTX - 1)) * 64;

    int wave = tid >> 6, lane = tid & 63;
    int wr = wave >> 1, wc = wave & 1;
    int l15 = lane & 15, lg = lane >> 4;

    f32x4 acc[2][2];
    #pragma unroll
    for (int m = 0; m < 2; ++m)
        #pragma unroll
        for (int n = 0; n < 2; ++n)
            acc[m][n] = (f32x4){0.f, 0.f, 0.f, 0.f};

    int r0 = tid >> 3, u0 = tid & 7;
    int r1 = r0 + 32, u1 = u0;

    const ushort_t* pa0 = A  + (size_t)(m0 + r0) * Kdim + u0 * 8;
    const ushort_t* pa1 = A  + (size_t)(m0 + r1) * Kdim + u1 * 8;
    const ushort_t* pb0 = BT + (size_t)(n0 + r0) * Kdim + u0 * 8;
    const ushort_t* pb1 = BT + (size_t)(n0 + r1) * Kdim + u1 * 8;

    uint4 a0 = *(const uint4*)(pa0);
    uint4 a1 = *(const uint4*)(pa1);
    uint4 b0 = *(const uint4*)(pb0);
    uint4 b1 = *(const uint4*)(pb1);

    for (int kt = 0; kt < Kdim; kt += 64) {
        __syncthreads();                       // prev iter's frag reads done
        *(uint4*)(As + r0 * LDB + u0 * 8) = a0;
        *(uint4*)(As + r1 * LDB + u1 * 8) = a1;
        *(uint4*)(Bs + r0 * LDB + u0 * 8) = b0;
        *(uint4*)(Bs + r1 * LDB + u1 * 8) = b1;
        __syncthreads();
        if (kt + 64 < Kdim) {                  // issue next loads early
            a0 = *(const uint4*)(pa0 + kt + 64);
            a1 = *(const uint4*)(pa1 + kt + 64);
            b0 = *(const uint4*)(pb0 + kt + 64);
            b1 = *(const uint4*)(pb1 + kt + 64);
        }
        #pragma unroll
        for (int kk = 0; kk < 2; ++kk) {
            bf16x8 af[2], bfr[2];
            #pragma unroll
            for (int m = 0; m < 2; ++m)
                af[m] = *(const bf16x8*)(As + (wr * 32 + m * 16 + l15) * LDB + (kk * 4 + lg) * 8);
            #pragma unroll
            for (int n = 0; n < 2; ++n)
                bfr[n] = *(const bf16x8*)(Bs + (wc * 32 + n * 16 + l15) * LDB + (kk * 4 + lg) * 8);
            #pragma unroll
            for (int m = 0; m < 2; ++m)
                #pragma unroll
                for (int n = 0; n < 2; ++n)
                    acc[m][n] = __builtin_amdgcn_mfma_f32_16x16x32_bf16(
                        af[m], bfr[n], acc[m][n], 0, 0, 0);
        }
    }
    #pragma unroll
    for (int m = 0; m < 2; ++m)
        #pragma unroll
        for (int n = 0; n < 2; ++n)
            #pragma unroll
            for (int q = 0; q < 4; ++q) {
                int row = m0 + wr * 32 + m * 16 + lg * 4 + q;
                int col = n0 + wc * 32 + n * 16 + l15;
                if (BF16OUT) {
                    __hip_bfloat16 hb = __float2bfloat16(acc[m][n][q]);
                    ((ushort_t*)Cv)[(size_t)row * Ndim + col] = *(ushort_t*)&hb;
                } else {
                    ((float*)Cv)[(size_t)row * Ndim + col] = acc[m][n][q];
                }
            }
}

// ================================================================ K3: pool (r16 verbatim; pk2 now HW cvt_pk)
__global__ __launch_bounds__(256, 8)
void pool_cells(const float* __restrict__ zc_off, const float* __restrict__ zc_on,
                const float* __restrict__ fake, const ushort_t* __restrict__ qkb,
                const int* __restrict__ counts, const int* __restrict__ lists,
                const int* __restrict__ ig_p, ushort_t* __restrict__ wout) {
    __shared__ __align__(16) ushort_t tok[NTOKMAX * E_];   // 18 KB, swizzled
    __shared__ float sc[H_ * 48];                          // 1.5 KB

    int g = blockIdx.x, s = g & (S_ - 1), b = g >> 10, tid = threadIdx.x;
    int h = tid >> 5, j = tid & 31;

    int cnt = min(counts[g], NCAP);
    int ntok = cnt + 1, ig = ig_p[0];
    const float* lastrow = ig ? fake : zc_on + (size_t)g * E_;

    {
        uint4* t4 = (uint4*)tok;
        for (int i = tid; i < ntok * 32; i += 256) {
            int p = i >> 5, q = i & 31;
            const float* src = (p < cnt)
                ? zc_off + ((size_t)b * U_ + lists[g * NLIST + p]) * E_
                : lastrow;
            float4 x = *(const float4*)(src + q * 8);
            float4 y = *(const float4*)(src + q * 8 + 4);
            uint4 o;
            o.x = pk2(x.x, x.y); o.y = pk2(x.z, x.w);
            o.z = pk2(y.x, y.y); o.w = pk2(y.z, y.w);
            t4[((p << 5) + q) ^ (p & 7)] = o;
        }
    }
    __syncthreads();

    if (tid < 64) {
        int l15 = tid & 15, lg = tid >> 4;
        bf16x8 af[8];
        const ushort_t* qrow = qkb + (size_t)s * KDIM + l15 * E_ + lg * 8;
        #pragma unroll
        for (int kk = 0; kk < 8; ++kk)
            af[kk] = *(const bf16x8*)(qrow + kk * 32);
        const bf16x8* tv = (const bf16x8*)tok;
        int ntiles = (ntok + 15) >> 4;
        for (int t = 0; t < ntiles; ++t) {
            f32x4 acc = (f32x4){0.f, 0.f, 0.f, 0.f};
            int row = t * 16 + l15;
            int rc = row < NTOKMAX ? row : NTOKMAX - 1;
            #pragma unroll
            for (int kk = 0; kk < 8; ++kk) {
                bf16x8 bfr = tv[((rc << 5) + (kk << 2) + lg) ^ (rc & 7)];
                acc = __builtin_amdgcn_mfma_f32_16x16x32_bf16(af[kk], bfr, acc, 0, 0, 0);
            }
            if (lg < 2) {
                #pragma unroll
                for (int q = 0; q < 4; ++q)
                    sc[(lg * 4 + q) * 48 + t * 16 + l15] = acc[q];
            }
        }
    }
    __syncthreads();

    {
        float v0 = (j < ntok) ? sc[h * 48 + j] : -1e30f;
        float v1 = (j + 32 < ntok) ? sc[h * 48 + j + 32] : -1e30f;
        float mx = fmaxf(v0, v1);
        #pragma unroll
        for (int off = 16; off; off >>= 1) mx = fmaxf(mx, __shfl_xor(mx, off, 32));
        float e0 = (j < ntok) ? __expf(v0 - mx) : 0.f;
        float e1 = (j + 32 < ntok) ? __expf(v1 - mx) : 0.f;
        float sm = e0 + e1;
        #pragma unroll
        for (int off = 16; off; off >>= 1) sm += __shfl_xor(sm, off, 32);
        float inv = 1.f / sm;
        if (j < ntok)      sc[h * 48 + j] = e0 * inv;
        if (j + 32 < ntok) sc[h * 48 + j + 32] = e1 * inv;
    }
    // no barrier: same 32-lane group, wave program order (r10-r16 verified)

    float acc[8];
    #pragma unroll
    for (int k = 0; k < 8; ++k) acc[k] = 0.f;
    const bf16x8* tv2 = (const bf16x8*)tok;
    for (int p = 0; p < ntok; ++p) {
        float a = sc[h * 48 + p];
        bf16x8 t8 = tv2[((p << 5) + j) ^ (p & 7)];
        #pragma unroll
        for (int k = 0; k < 8; ++k) acc[k] += a * ubf((ushort_t)t8[k]);
    }
    uint4 o;
    o.x = pk2(acc[0], acc[1]); o.y = pk2(acc[2], acc[3]);
    o.z = pk2(acc[4], acc[5]); o.w = pk2(acc[6], acc[7]);
    ((uint4*)(wout + (size_t)g * KDIM))[tid] = o;
}

// ================================================================ launch — 4 graph nodes (r16 verbatim)
extern "C" void kernel_launch(void* const* d_in, const int* in_sizes, int n_in,
                              void* d_out, int out_size, void* d_ws, size_t ws_size,
                              hipStream_t stream) {
    const float* xc_off  = (const float*)d_in[0];
    const float* xc_on   = (const float*)d_in[1];
    const float* zc_off  = (const float*)d_in[2];
    const float* zc_on   = (const float*)d_in[3];
    const float* latents = (const float*)d_in[4];
    const float* fake    = (const float*)d_in[5];
    const float* Wq      = (const float*)d_in[6];
    const float* Wk      = (const float*)d_in[7];
    const float* Wv      = (const float*)d_in[8];
    const float* Wo      = (const float*)d_in[9];
    const int*   ig      = (const int*)d_in[10];
    float* out = (float*)d_out;

    char* ws = (char*)d_ws;
    int*      counts = (int*)(ws + WS_COUNTS);
    int*      lists  = (int*)(ws + WS_LISTS);
    ushort_t* latb   = (ushort_t*)(ws + WS_LATB);
    ushort_t* wqkT   = (ushort_t*)(ws + WS_WQKT);
    ushort_t* wvoT   = (ushort_t*)(ws + WS_WVOT);
    ushort_t* qkb    = (ushort_t*)(ws + WS_QKB);
    ushort_t* w      = (ushort_t*)(ws + WS_W);

    const int PASS = B_ * N_ * N_ * 2;   // 16384 floats

    // node 1: latb + WqkT + WvoT + counts-zero + passthrough (240 blocks)
    prep<<<240, 256, 0, stream>>>(latents, Wq, Wk, Wv, Wo, xc_on, out,
                                  counts, latb, wqkT, wvoT);

    // node 2: qkb = latb @ WqkT (M=1024 N=2048 K=256, 512 blocks, lgNTX=5)
    //         + build_lists (blocks 512..767)
    gemm_k<true, true><<<GEMMBLK + 256, 256, 0, stream>>>(
        latb, wqkT, qkb, 256, KDIM, 5, xc_off, counts, lists);

    // node 3: pool
    pool_cells<<<GCELLS, 256, 0, stream>>>(zc_off, zc_on, fake, qkb,
                                           counts, lists, ig, w);

    // node 4: out = w @ Wvo (M=8192 N=256 K=2048, 512 blocks, lgNTX=2)
    gemm_k<false, false><<<GEMMBLK, 256, 0, stream>>>(
        w, wvoT, out + PASS, KDIM, E_, 2, nullptr, nullptr, nullptr);
}